// Round 9
// baseline (3030.038 us; speedup 1.0000x reference)
//
#include <hip/hip_runtime.h>
#include <stdint.h>

#define B_ 32
#define S_ 512
#define I_ 256
#define H_ 512
#define OUTW 1024
#define OUTS_ELEMS (B_*S_*OUTW)   // 16777216

typedef _Float16 f16;
typedef _Float16 half2_t __attribute__((ext_vector_type(2)));

__device__ __forceinline__ float fdot2(uint32_t a, uint32_t b, float c){
#if __has_builtin(__builtin_amdgcn_fdot2)
  return __builtin_amdgcn_fdot2(__builtin_bit_cast(half2_t, a),
                                __builtin_bit_cast(half2_t, b), c, false);
#else
  half2_t ha = __builtin_bit_cast(half2_t, a);
  half2_t hb = __builtin_bit_cast(half2_t, b);
  return c + (float)ha.x*(float)hb.x + (float)ha.y*(float)hb.y;
#endif
}

__device__ __forceinline__ uint32_t packf16(float x, float y){
  union { f16 h[2]; uint32_t u; } z;
  z.h[0] = (f16)x; z.h[1] = (f16)y;
  return z.u;
}

template<int CTRL>
__device__ __forceinline__ float dpp_add(float x){
  int v = __builtin_amdgcn_update_dpp(0, __float_as_int(x), CTRL, 0xF, 0xF, true);
  return x + __int_as_float(v);
}
// full-wave (64 lane) sum; valid in lane 63. Pure VALU (DPP), no LDS pipe.
__device__ __forceinline__ float wave_total(float x){
  x = dpp_add<0x111>(x);   // row_shr:1
  x = dpp_add<0x112>(x);   // row_shr:2
  x = dpp_add<0x114>(x);   // row_shr:4
  x = dpp_add<0x118>(x);   // row_shr:8
  x = dpp_add<0x142>(x);   // row_bcast:15
  x = dpp_add<0x143>(x);   // row_bcast:31
  return x;
}

// ---------------------------------------------------------------------------
// P0: W_hh fp32 -> f16 into d_ws
// ---------------------------------------------------------------------------
__global__ __launch_bounds__(256) void cvt_w_kernel(const float* __restrict__ wf,
                                                    const float* __restrict__ wb,
                                                    f16* __restrict__ out){
  int i = blockIdx.x*256 + threadIdx.x;
  const float* src = (i < 32768) ? wf : wb;
  int base = (i & 32767) * 8;
  float4 a = *(const float4*)(src + base);
  float4 c = *(const float4*)(src + base + 4);
  uint4 o;
  o.x = packf16(a.x, a.y); o.y = packf16(a.z, a.w);
  o.z = packf16(c.x, c.y); o.w = packf16(c.z, c.w);
  *(uint4*)(out + (size_t)i*8) = o;
}

// ---------------------------------------------------------------------------
// P1: xp staged into d_out (read once by rnn, then overwritten with h).
// ---------------------------------------------------------------------------
#define PTM 128
#define PTN 64
#define PTK 32
__global__ __launch_bounds__(256) void proj_kernel(
    const float* __restrict__ x,
    const float* __restrict__ wihf, const float* __restrict__ wihb,
    const float* __restrict__ bihf, const float* __restrict__ bhhf,
    const float* __restrict__ bihb, const float* __restrict__ bhhb,
    float* __restrict__ out)
{
  __shared__ float As[PTK][132];
  __shared__ float Bs[PTK][68];
  const int tid = threadIdx.x;
  const int row0 = blockIdx.x * PTM;
  const int j0   = blockIdx.y * PTN;
  const int dir  = (j0 >= 512) ? 1 : 0;
  const int jl0  = j0 - dir*512;
  const float* wih = dir ? wihb : wihf;
  const float* bi  = dir ? bihb : bihf;
  const float* bh  = dir ? bhhb : bhhf;

  const int ty = tid >> 4, tx = tid & 15;
  float acc[8][4];
#pragma unroll
  for (int i=0;i<8;i++)
#pragma unroll
    for (int j=0;j<4;j++) acc[i][j] = 0.f;

  float bias[4];
#pragma unroll
  for (int jj=0;jj<4;jj++){ int jl = jl0 + tx*4 + jj; bias[jj] = bi[jl] + bh[jl]; }

  for (int k0 = 0; k0 < I_; k0 += PTK){
    {
      int r = tid >> 1, kh = (tid & 1) * 16;
      int rg = row0 + r; int bb = rg & 31, tt = rg >> 5;
      const float* ap = x + ((size_t)bb*S_ + tt)*I_ + k0 + kh;
#pragma unroll
      for (int u=0;u<4;u++){
        float4 v = *(const float4*)(ap + u*4);
        As[kh+u*4+0][r] = v.x; As[kh+u*4+1][r] = v.y;
        As[kh+u*4+2][r] = v.z; As[kh+u*4+3][r] = v.w;
      }
    }
    {
      int jr = tid >> 2, kh = (tid & 3) * 8;
      const float* bp = wih + (size_t)(jl0 + jr)*I_ + k0 + kh;
#pragma unroll
      for (int u=0;u<2;u++){
        float4 v = *(const float4*)(bp + u*4);
        Bs[kh+u*4+0][jr] = v.x; Bs[kh+u*4+1][jr] = v.y;
        Bs[kh+u*4+2][jr] = v.z; Bs[kh+u*4+3][jr] = v.w;
      }
    }
    __syncthreads();
#pragma unroll 8
    for (int kk=0; kk<PTK; ++kk){
      const float4 a0 = *(const float4*)&As[kk][ty*8+0];
      const float4 a1 = *(const float4*)&As[kk][ty*8+4];
      const float4 bq = *(const float4*)&Bs[kk][tx*4];
      const float av[8] = {a0.x,a0.y,a0.z,a0.w,a1.x,a1.y,a1.z,a1.w};
      const float bv[4] = {bq.x,bq.y,bq.z,bq.w};
#pragma unroll
      for (int i=0;i<8;i++)
#pragma unroll
        for (int j=0;j<4;j++) acc[i][j] = fmaf(av[i], bv[j], acc[i][j]);
    }
    __syncthreads();
  }
#pragma unroll
  for (int i=0;i<8;i++){
    int rg = row0 + ty*8 + i; int bb = rg & 31, tt = rg >> 5;
    float* op = out + ((size_t)bb*S_ + tt)*OUTW + j0 + tx*4;
    float4 v = {acc[i][0]+bias[0], acc[i][1]+bias[1], acc[i][2]+bias[2], acc[i][3]+bias[3]};
    *(float4*)op = v;
  }
}

// ---------------------------------------------------------------------------
// R: row-split recurrence, W in LDS, h-broadcast via narrow tagged mailbox.
// 32 groups (dir, batch-pair) x 8 WGs(q) = 256 WGs x 512 thr; LDS padded to
// 96KB -> 1 WG/CU, all co-resident. WG q owns rows [q*64,+64) with FULL k:
// complete dots in-CU (W block 64x512 f16 = 64KB LDS, read once per step,
// shared by both batches). Wave rg handles rows rowbase=q*64+rg*8..+8; lane
// l covers k = l*8+[0,8). Reduce over 64 lanes = 6 DPP adds (VALU only),
// total lands in lane 63, which finalizes 8 CONTIGUOUS rows: vectorized xp
// float4 loads (issued early), relu, float4 out stores, 16 tagged-dword mail
// stores, one b128 LDS write of own h. Consumers spin on 2 dwords/lane
// (448 remote rows). Mail = 128 dw/WG/step = 67MB total (r2 level).
// ---------------------------------------------------------------------------
#define HLDS_OFF 65536
#define LDS_TOTAL 98304            // pad 66KB -> 96KB: forces 1 WG/CU
#define MAIL_OFF_U32 (1u<<18)      // W f16 = 1 MB = 2^18 u32
#define MAIL_U32     (64*2*512)    // [chain][parity][row] = 256 KB
#define MAIL_BYTES   (MAIL_U32*4)

__global__ __launch_bounds__(512) void rnn_kernel(
    const f16* __restrict__ Wall,   // [2][512][512] f16
    const float* __restrict__ h0,   // [2][32][512]
    float* dout, uint32_t* mailbase)
{
  extern __shared__ char lds[];
  const int tid = threadIdx.x;
  const int G   = blockIdx.x & 31;
  const int q   = blockIdx.x >> 5;        // owned-row block; group blocks G+32q -> same XCD
  const int dir = G >> 4;
  const int b0  = (G & 15) * 2;
  const int rg  = tid >> 6;               // wave in [0,8)
  const int l   = tid & 63;

  const f16* Wd = Wall + (size_t)dir * (H_*(size_t)H_);

  // ---- stage W rows [q*64,+64), all k, row-major [64][512] f16
  {
    const int r = tid >> 3, c = tid & 7;
    const f16* src = Wd + (size_t)(q*64 + r)*H_ + c*64;
    char* dst = lds + r*1024 + c*128;
#pragma unroll
    for (int i=0;i<8;i++)
      *(uint4*)(dst + i*16) = *(const uint4*)(src + i*8);
  }
  // ---- stage h0 (both chains): h[ch] at HLDS_OFF + ch*1024 + row*2
  {
    *(f16*)(lds + HLDS_OFF +        tid*2) = (f16)h0[((size_t)dir*B_ + b0  )*H_ + tid];
    *(f16*)(lds + HLDS_OFF + 1024 + tid*2) = (f16)h0[((size_t)dir*B_ + b0+1)*H_ + tid];
  }
  __syncthreads();

  const int ch0 = G*2, ch1 = G*2 + 1;
  float* outs0 = dout + (size_t)(b0  )*(S_*OUTW);
  float* outs1 = dout + (size_t)(b0+1)*(S_*OUTW);
  float* hn0 = dout + (size_t)OUTS_ELEMS + ((size_t)dir*B_ + b0  )*H_;
  float* hn1 = dout + (size_t)OUTS_ELEMS + ((size_t)dir*B_ + b0+1)*H_;
  const int rowbase = q*64 + rg*8;        // publisher's 8 contiguous rows
  const int colbase = dir*512 + rowbase;
  const bool isPub  = (l == 63);
  const bool remote = (tid >> 6) != q;    // row tid not finalized by this WG
  uint32_t* mb = mailbase;

  for (int s=0; s<S_; ++s){
    const int t = dir ? (S_-1-s) : s;
    float* xo0 = outs0 + (size_t)t*OUTW;
    float* xo1 = outs1 + (size_t)t*OUTW;
    float4 xa0, xb0, xa1, xb1;
    if (isPub){                           // issue early; used after compute
      xa0 = *(const float4*)(xo0 + colbase);
      xb0 = *(const float4*)(xo0 + colbase + 4);
      xa1 = *(const float4*)(xo1 + colbase);
      xb1 = *(const float4*)(xo1 + colbase + 4);
    }
    // ---- receive remote h (tag s, parity s&1) and stage into LDS
    if (s > 0 && remote){
      const uint32_t tag = (uint32_t)s;
      const int P = s & 1;
      uint32_t* p0 = mb + (size_t)(ch0*2 + P)*512 + tid;
      uint32_t* p1 = mb + (size_t)(ch1*2 + P)*512 + tid;
      uint32_t v0, v1;
      do { v0 = __hip_atomic_load(p0, __ATOMIC_RELAXED, __HIP_MEMORY_SCOPE_AGENT);
      } while ((v0 & 0xffffu) != tag);
      do { v1 = __hip_atomic_load(p1, __ATOMIC_RELAXED, __HIP_MEMORY_SCOPE_AGENT);
      } while ((v1 & 0xffffu) != tag);
      *(f16*)(lds + HLDS_OFF +        tid*2) = __builtin_bit_cast(f16, (uint16_t)(v0 >> 16));
      *(f16*)(lds + HLDS_OFF + 1024 + tid*2) = __builtin_bit_cast(f16, (uint16_t)(v1 >> 16));
    }
    __syncthreads();

    // ---- compute: 8 rows x (8 k per lane), both chains share the W read
    const uint4 h0v = *(const uint4*)(lds + HLDS_OFF +        l*16);
    const uint4 h1v = *(const uint4*)(lds + HLDS_OFF + 1024 + l*16);
    float t0[8], t1[8];
#pragma unroll
    for (int rr=0; rr<8; ++rr){
      const uint4 w = *(const uint4*)(lds + (rg*8 + rr)*1024 + l*16);
      float a = 0.f, b = 0.f;
      a=fdot2(w.x,h0v.x,a); a=fdot2(w.y,h0v.y,a); a=fdot2(w.z,h0v.z,a); a=fdot2(w.w,h0v.w,a);
      b=fdot2(w.x,h1v.x,b); b=fdot2(w.y,h1v.y,b); b=fdot2(w.z,h1v.z,b); b=fdot2(w.w,h1v.w,b);
      t0[rr] = wave_total(a);             // valid in lane 63
      t1[rr] = wave_total(b);
    }
    __syncthreads();                      // all h reads done before h rewrite

    // ---- lane 63 finalizes its wave's 8 contiguous rows, both chains
    if (isPub){
      const uint32_t tagn = (uint32_t)(s+1);
      const int Pn = (s+1) & 1;
      float h00=fmaxf(xa0.x+t0[0],0.f), h01=fmaxf(xa0.y+t0[1],0.f);
      float h02=fmaxf(xa0.z+t0[2],0.f), h03=fmaxf(xa0.w+t0[3],0.f);
      float h04=fmaxf(xb0.x+t0[4],0.f), h05=fmaxf(xb0.y+t0[5],0.f);
      float h06=fmaxf(xb0.z+t0[6],0.f), h07=fmaxf(xb0.w+t0[7],0.f);
      float h10=fmaxf(xa1.x+t1[0],0.f), h11=fmaxf(xa1.y+t1[1],0.f);
      float h12=fmaxf(xa1.z+t1[2],0.f), h13=fmaxf(xa1.w+t1[3],0.f);
      float h14=fmaxf(xb1.x+t1[4],0.f), h15=fmaxf(xb1.y+t1[5],0.f);
      float h16=fmaxf(xb1.z+t1[6],0.f), h17=fmaxf(xb1.w+t1[7],0.f);
      // outputs (overwrite xp slots)
      *(float4*)(xo0 + colbase)     = (float4){h00,h01,h02,h03};
      *(float4*)(xo0 + colbase + 4) = (float4){h04,h05,h06,h07};
      *(float4*)(xo1 + colbase)     = (float4){h10,h11,h12,h13};
      *(float4*)(xo1 + colbase + 4) = (float4){h14,h15,h16,h17};
      if (s == S_-1){
        *(float4*)(hn0 + rowbase)     = (float4){h00,h01,h02,h03};
        *(float4*)(hn0 + rowbase + 4) = (float4){h04,h05,h06,h07};
        *(float4*)(hn1 + rowbase)     = (float4){h10,h11,h12,h13};
        *(float4*)(hn1 + rowbase + 4) = (float4){h14,h15,h16,h17};
      }
      // own-row h into LDS (16B each chain)
      *(uint4*)(lds + HLDS_OFF +        rowbase*2) =
          (uint4){packf16(h00,h01), packf16(h02,h03), packf16(h04,h05), packf16(h06,h07)};
      *(uint4*)(lds + HLDS_OFF + 1024 + rowbase*2) =
          (uint4){packf16(h10,h11), packf16(h12,h13), packf16(h14,h15), packf16(h16,h17)};
      // mailbox publish: 8 tagged dwords per chain
      uint32_t* w0 = mb + (size_t)(ch0*2 + Pn)*512 + rowbase;
      uint32_t* w1 = mb + (size_t)(ch1*2 + Pn)*512 + rowbase;
      const float hc0[8] = {h00,h01,h02,h03,h04,h05,h06,h07};
      const float hc1[8] = {h10,h11,h12,h13,h14,h15,h16,h17};
#pragma unroll
      for (int rr=0; rr<8; ++rr){
        uint32_t u0 = ((uint32_t)__builtin_bit_cast(uint16_t, (f16)hc0[rr]) << 16) | tagn;
        uint32_t u1 = ((uint32_t)__builtin_bit_cast(uint16_t, (f16)hc1[rr]) << 16) | tagn;
        __hip_atomic_store(w0 + rr, u0, __ATOMIC_RELAXED, __HIP_MEMORY_SCOPE_AGENT);
        __hip_atomic_store(w1 + rr, u1, __ATOMIC_RELAXED, __HIP_MEMORY_SCOPE_AGENT);
      }
    }
    // next iter's spin-writes touch only remote rows; barrier at its top
    // (barrier1) orders publisher's LDS writes vs. next compute reads.
  }
}

// ---------------------------------------------------------------------------
extern "C" void kernel_launch(void* const* d_in, const int* in_sizes, int n_in,
                              void* d_out, int out_size, void* d_ws, size_t ws_size,
                              hipStream_t stream){
  const float* x    = (const float*)d_in[0];
  const float* h0   = (const float*)d_in[1];
  const float* wihf = (const float*)d_in[2];
  const float* whhf = (const float*)d_in[3];
  const float* bihf = (const float*)d_in[4];
  const float* bhhf = (const float*)d_in[5];
  const float* wihb = (const float*)d_in[6];
  const float* whhb = (const float*)d_in[7];
  const float* bihb = (const float*)d_in[8];
  const float* bhhb = (const float*)d_in[9];
  float* out = (float*)d_out;
  f16* wf16 = (f16*)d_ws;                            // 1 MB
  uint32_t* mail = (uint32_t*)d_ws + MAIL_OFF_U32;   // 256 KB

  hipMemsetAsync((void*)mail, 0, MAIL_BYTES, stream);  // kill stale tags across replays
  cvt_w_kernel<<<256, 256, 0, stream>>>(whhf, whhb, wf16);
  proj_kernel<<<dim3(128, 16), 256, 0, stream>>>(x, wihf, wihb, bihf, bhhf, bihb, bhhb, out);
  (void)hipFuncSetAttribute((const void*)rnn_kernel,
                            hipFuncAttributeMaxDynamicSharedMemorySize, LDS_TOTAL);
  rnn_kernel<<<256, 512, LDS_TOTAL, stream>>>(wf16, h0, out, mail);
}

// Round 10
// 1621.195 us; speedup vs baseline: 1.8690x; 1.8690x over previous
//
#include <hip/hip_runtime.h>
#include <stdint.h>

#define B_ 32
#define S_ 512
#define I_ 256
#define H_ 512
#define OUTW 1024
#define OUTS_ELEMS (B_*S_*OUTW)   // 16777216

typedef _Float16 f16;
typedef _Float16 half2_t __attribute__((ext_vector_type(2)));

__device__ __forceinline__ float fdot2(uint32_t a, uint32_t b, float c){
#if __has_builtin(__builtin_amdgcn_fdot2)
  return __builtin_amdgcn_fdot2(__builtin_bit_cast(half2_t, a),
                                __builtin_bit_cast(half2_t, b), c, false);
#else
  half2_t ha = __builtin_bit_cast(half2_t, a);
  half2_t hb = __builtin_bit_cast(half2_t, b);
  return c + (float)ha.x*(float)hb.x + (float)ha.y*(float)hb.y;
#endif
}

__device__ __forceinline__ uint32_t packf16(float x, float y){
  union { f16 h[2]; uint32_t u; } z;
  z.h[0] = (f16)x; z.h[1] = (f16)y;
  return z.u;
}

template<int CTRL>
__device__ __forceinline__ float dpp_add(float x){
  int v = __builtin_amdgcn_update_dpp(0, __float_as_int(x), CTRL, 0xF, 0xF, true);
  return x + __int_as_float(v);
}

// 8 accs (rows i=0..7), each summed over all 64 lanes; lane l returns the
// FULL total of acc (l&7). 16 quad-DPP + 5 shuffles, all wave-uniform.
__device__ __forceinline__ float reduce64(float a0,float a1,float a2,float a3,
                                          float a4,float a5,float a6,float a7,
                                          int m){
  a0=dpp_add<0xB1>(a0); a1=dpp_add<0xB1>(a1); a2=dpp_add<0xB1>(a2); a3=dpp_add<0xB1>(a3);
  a4=dpp_add<0xB1>(a4); a5=dpp_add<0xB1>(a5); a6=dpp_add<0xB1>(a6); a7=dpp_add<0xB1>(a7);
  a0=dpp_add<0x4E>(a0); a1=dpp_add<0x4E>(a1); a2=dpp_add<0x4E>(a2); a3=dpp_add<0x4E>(a3);
  a4=dpp_add<0x4E>(a4); a5=dpp_add<0x4E>(a5); a6=dpp_add<0x4E>(a6); a7=dpp_add<0x4E>(a7);
  const int k3 = m & 3;
  float lo = (k3==0)?a0:(k3==1)?a1:(k3==2)?a2:a3;
  float hi = (k3==0)?a4:(k3==1)?a5:(k3==2)?a6:a7;
  lo += __shfl_xor(lo, 4);
  hi += __shfl_xor(hi, 4);
  float v = (m<4) ? lo : hi;       // group-of-8 sum of acc m
  v += __shfl_xor(v, 8);
  v += __shfl_xor(v, 16);
  v += __shfl_xor(v, 32);          // full 64-lane total of acc m
  return v;
}

#define DOTROW(ACC, WV, HV) \
  ACC=fdot2(WV.x,HV.x,ACC); ACC=fdot2(WV.y,HV.y,ACC); \
  ACC=fdot2(WV.z,HV.z,ACC); ACC=fdot2(WV.w,HV.w,ACC);

// ---------------------------------------------------------------------------
// P0: W_hh fp32 -> f16 into d_ws
// ---------------------------------------------------------------------------
__global__ __launch_bounds__(256) void cvt_w_kernel(const float* __restrict__ wf,
                                                    const float* __restrict__ wb,
                                                    f16* __restrict__ out){
  int i = blockIdx.x*256 + threadIdx.x;
  const float* src = (i < 32768) ? wf : wb;
  int base = (i & 32767) * 8;
  float4 a = *(const float4*)(src + base);
  float4 c = *(const float4*)(src + base + 4);
  uint4 o;
  o.x = packf16(a.x, a.y); o.y = packf16(a.z, a.w);
  o.z = packf16(c.x, c.y); o.w = packf16(c.z, c.w);
  *(uint4*)(out + (size_t)i*8) = o;
}

// ---------------------------------------------------------------------------
// P1: xp staged into d_out (read once by rnn, then overwritten with h).
// ---------------------------------------------------------------------------
#define PTM 128
#define PTN 64
#define PTK 32
__global__ __launch_bounds__(256) void proj_kernel(
    const float* __restrict__ x,
    const float* __restrict__ wihf, const float* __restrict__ wihb,
    const float* __restrict__ bihf, const float* __restrict__ bhhf,
    const float* __restrict__ bihb, const float* __restrict__ bhhb,
    float* __restrict__ out)
{
  __shared__ float As[PTK][132];
  __shared__ float Bs[PTK][68];
  const int tid = threadIdx.x;
  const int row0 = blockIdx.x * PTM;
  const int j0   = blockIdx.y * PTN;
  const int dir  = (j0 >= 512) ? 1 : 0;
  const int jl0  = j0 - dir*512;
  const float* wih = dir ? wihb : wihf;
  const float* bi  = dir ? bihb : bihf;
  const float* bh  = dir ? bhhb : bhhf;

  const int ty = tid >> 4, tx = tid & 15;
  float acc[8][4];
#pragma unroll
  for (int i=0;i<8;i++)
#pragma unroll
    for (int j=0;j<4;j++) acc[i][j] = 0.f;

  float bias[4];
#pragma unroll
  for (int jj=0;jj<4;jj++){ int jl = jl0 + tx*4 + jj; bias[jj] = bi[jl] + bh[jl]; }

  for (int k0 = 0; k0 < I_; k0 += PTK){
    {
      int r = tid >> 1, kh = (tid & 1) * 16;
      int rg = row0 + r; int bb = rg & 31, tt = rg >> 5;
      const float* ap = x + ((size_t)bb*S_ + tt)*I_ + k0 + kh;
#pragma unroll
      for (int u=0;u<4;u++){
        float4 v = *(const float4*)(ap + u*4);
        As[kh+u*4+0][r] = v.x; As[kh+u*4+1][r] = v.y;
        As[kh+u*4+2][r] = v.z; As[kh+u*4+3][r] = v.w;
      }
    }
    {
      int jr = tid >> 2, kh = (tid & 3) * 8;
      const float* bp = wih + (size_t)(jl0 + jr)*I_ + k0 + kh;
#pragma unroll
      for (int u=0;u<2;u++){
        float4 v = *(const float4*)(bp + u*4);
        Bs[kh+u*4+0][jr] = v.x; Bs[kh+u*4+1][jr] = v.y;
        Bs[kh+u*4+2][jr] = v.z; Bs[kh+u*4+3][jr] = v.w;
      }
    }
    __syncthreads();
#pragma unroll 8
    for (int kk=0; kk<PTK; ++kk){
      const float4 a0 = *(const float4*)&As[kk][ty*8+0];
      const float4 a1 = *(const float4*)&As[kk][ty*8+4];
      const float4 bq = *(const float4*)&Bs[kk][tx*4];
      const float av[8] = {a0.x,a0.y,a0.z,a0.w,a1.x,a1.y,a1.z,a1.w};
      const float bv[4] = {bq.x,bq.y,bq.z,bq.w};
#pragma unroll
      for (int i=0;i<8;i++)
#pragma unroll
        for (int j=0;j<4;j++) acc[i][j] = fmaf(av[i], bv[j], acc[i][j]);
    }
    __syncthreads();
  }
#pragma unroll
  for (int i=0;i<8;i++){
    int rg = row0 + ty*8 + i; int bb = rg & 31, tt = rg >> 5;
    float* op = out + ((size_t)bb*S_ + tt)*OUTW + j0 + tx*4;
    float4 v = {acc[i][0]+bias[0], acc[i][1]+bias[1], acc[i][2]+bias[2], acc[i][3]+bias[3]};
    *(float4*)op = v;
  }
}

// ---------------------------------------------------------------------------
// R: 8-way ROW-split, 2 chains/CU, W in LDS, h-broadcast mailbox.
// 32 groups (dir, batch-pair) x 8 WGs(q) = 256 WGs x 512 thr; LDS padded to
// 84 KB -> exactly 1 WG/CU (co-resident, deadlock-free).
// WG q owns rows [q*64,+64) with FULL k: W block 64x512 f16 = 64 KB LDS,
// read ONCE per step, shared by both chains. Wave w, lane l: rows w*8+i
// (i=0..7), k-segment [8l,8l+8) -> per lane 8 W b128 + 2 h b128 per step.
// reduce64 leaves row-total of row w*8+(l&7) in EVERY lane; lanes l<8
// finalize+publish: coalesced 8-dword mail store per wave per chain.
// Consumers (448 remote rows): spin on ONE dword per chain (both chains in
// one loop), stage f16 into parity-swapped h-LDS. One barrier per step.
// Schedule: compute c0 -> publish c0 -> compute c1 -> publish c1 -> spin c0
// -> spin c1: c0's mailbox flight hides under c1's compute.
// ---------------------------------------------------------------------------
#define HLDS 65536                 // h region: [ch][par][512 f16] = 4 KB
#define LDS_TOTAL 86016            // pad 68 KB -> 84 KB: forces 1 WG/CU
#define MAIL_OFF_U32 (1u<<18)      // W f16 = 1 MB = 2^18 u32
#define MAIL_U32     (64*2*512)    // [chain][parity][row] = 256 KB
#define MAIL_BYTES   (MAIL_U32*4)

__global__ __launch_bounds__(512) void rnn_kernel(
    const f16* __restrict__ Wall,   // [2][512][512] f16
    const float* __restrict__ h0,   // [2][32][512]
    float* dout, uint32_t* mailbase)
{
  extern __shared__ char lds[];
  const int tid = threadIdx.x;
  const int G   = blockIdx.x & 31;
  const int q   = blockIdx.x >> 5;        // owned-row block; blocks G+32q -> same XCD
  const int dir = G >> 4;
  const int b0  = (G & 15) * 2;
  const int w   = tid >> 6;               // wave in [0,8)
  const int l   = tid & 63;
  const int m   = l & 7;

  const f16* Wd = Wall + (size_t)dir * (H_*(size_t)H_);

  // ---- stage W rows [q*64,+64), all k, row-major [64][512] f16 (64 KB)
  {
    const int r = tid >> 3, seg = tid & 7;
    const f16* src = Wd + (size_t)(q*64 + r)*H_ + seg*64;
    char* dst = lds + r*1024 + seg*128;
#pragma unroll
    for (int i=0;i<8;i++)
      *(uint4*)(dst + i*16) = *(const uint4*)(src + i*8);
  }
  // ---- stage h0 (both chains, parity 0): off = HLDS + ch*2048 + par*1024 + row*2
  {
    *(f16*)(lds + HLDS +        tid*2) = (f16)h0[((size_t)dir*B_ + b0  )*H_ + tid];
    *(f16*)(lds + HLDS + 2048 + tid*2) = (f16)h0[((size_t)dir*B_ + b0+1)*H_ + tid];
  }
  __syncthreads();

  const bool isPub  = (l < 8);
  const int  prow   = q*64 + w*8 + l;     // publisher's global row (valid if isPub)
  const int  pcol   = dir*512 + prow;
  const bool remote = ((tid >> 6) != q);  // consumer row `tid` not owned here

  float* outs0 = dout + (size_t)(b0  )*(S_*OUTW);
  float* outs1 = dout + (size_t)(b0+1)*(S_*OUTW);
  float* hn0 = dout + (size_t)OUTS_ELEMS + ((size_t)dir*B_ + b0  )*H_;
  float* hn1 = dout + (size_t)OUTS_ELEMS + ((size_t)dir*B_ + b0+1)*H_;
  uint32_t* mail0 = mailbase + (size_t)(G*2    )*1024;   // [par][512]
  uint32_t* mail1 = mailbase + (size_t)(G*2 + 1)*1024;

  for (int s=0; s<S_; ++s){
    const int P = s & 1, Pn = P ^ 1;
    const int t = dir ? (S_-1-s) : s;
    const uint32_t tag = (uint32_t)(s+1);
    float* xo0 = outs0 + (size_t)t*OUTW;
    float* xo1 = outs1 + (size_t)t*OUTW;
    float xp0 = 0.f, xp1 = 0.f;
    if (isPub){ xp0 = xo0[pcol]; xp1 = xo1[pcol]; }   // long-latency, hidden

    // ---- W fragments (one read, both chains) + h fragments
    const uint4 w0 = *(const uint4*)(lds + (w*8+0)*1024 + l*16);
    const uint4 w1 = *(const uint4*)(lds + (w*8+1)*1024 + l*16);
    const uint4 w2 = *(const uint4*)(lds + (w*8+2)*1024 + l*16);
    const uint4 w3 = *(const uint4*)(lds + (w*8+3)*1024 + l*16);
    const uint4 w4 = *(const uint4*)(lds + (w*8+4)*1024 + l*16);
    const uint4 w5 = *(const uint4*)(lds + (w*8+5)*1024 + l*16);
    const uint4 w6 = *(const uint4*)(lds + (w*8+6)*1024 + l*16);
    const uint4 w7 = *(const uint4*)(lds + (w*8+7)*1024 + l*16);
    const uint4 h0v = *(const uint4*)(lds + HLDS +        P*1024 + l*16);
    const uint4 h1v = *(const uint4*)(lds + HLDS + 2048 + P*1024 + l*16);

    // ---- chain 0: dots + reduce + finalize + publish (coalesced 8 dwords/wave)
    {
      float a0=0.f,a1=0.f,a2=0.f,a3=0.f,a4=0.f,a5=0.f,a6=0.f,a7=0.f;
      DOTROW(a0,w0,h0v) DOTROW(a1,w1,h0v) DOTROW(a2,w2,h0v) DOTROW(a3,w3,h0v)
      DOTROW(a4,w4,h0v) DOTROW(a5,w5,h0v) DOTROW(a6,w6,h0v) DOTROW(a7,w7,h0v)
      float tot = reduce64(a0,a1,a2,a3,a4,a5,a6,a7,m);
      if (isPub){
        float h = fmaxf(xp0 + tot, 0.f);
        xo0[pcol] = h;                               // overwrite xp slot
        if (s == S_-1) hn0[prow] = h;
        *(f16*)(lds + HLDS + Pn*1024 + prow*2) = (f16)h;
        uint32_t u = ((uint32_t)__builtin_bit_cast(uint16_t, (f16)h) << 16) | tag;
        __hip_atomic_store(mail0 + Pn*512 + prow, u,
                           __ATOMIC_RELAXED, __HIP_MEMORY_SCOPE_AGENT);
      }
    }
    // ---- chain 1: same (c0's mailbox flight hides under this compute)
    {
      float a0=0.f,a1=0.f,a2=0.f,a3=0.f,a4=0.f,a5=0.f,a6=0.f,a7=0.f;
      DOTROW(a0,w0,h1v) DOTROW(a1,w1,h1v) DOTROW(a2,w2,h1v) DOTROW(a3,w3,h1v)
      DOTROW(a4,w4,h1v) DOTROW(a5,w5,h1v) DOTROW(a6,w6,h1v) DOTROW(a7,w7,h1v)
      float tot = reduce64(a0,a1,a2,a3,a4,a5,a6,a7,m);
      if (isPub){
        float h = fmaxf(xp1 + tot, 0.f);
        xo1[pcol] = h;
        if (s == S_-1) hn1[prow] = h;
        *(f16*)(lds + HLDS + 2048 + Pn*1024 + prow*2) = (f16)h;
        uint32_t u = ((uint32_t)__builtin_bit_cast(uint16_t, (f16)h) << 16) | tag;
        __hip_atomic_store(mail1 + Pn*512 + prow, u,
                           __ATOMIC_RELAXED, __HIP_MEMORY_SCOPE_AGENT);
      }
    }
    // ---- consume: one dword per chain, both in one spin loop; stage to LDS
    if (remote){
      uint32_t* p0 = mail0 + Pn*512 + tid;
      uint32_t* p1 = mail1 + Pn*512 + tid;
      uint32_t v0, v1;
      do {
        v0 = __hip_atomic_load(p0, __ATOMIC_RELAXED, __HIP_MEMORY_SCOPE_AGENT);
        v1 = __hip_atomic_load(p1, __ATOMIC_RELAXED, __HIP_MEMORY_SCOPE_AGENT);
      } while ((((v0 ^ tag) | (v1 ^ tag)) & 0xffffu) != 0u);
      *(f16*)(lds + HLDS +        Pn*1024 + tid*2) = __builtin_bit_cast(f16, (uint16_t)(v0 >> 16));
      *(f16*)(lds + HLDS + 2048 + Pn*1024 + tid*2) = __builtin_bit_cast(f16, (uint16_t)(v1 >> 16));
    }
    __syncthreads();
  }
}

// ---------------------------------------------------------------------------
extern "C" void kernel_launch(void* const* d_in, const int* in_sizes, int n_in,
                              void* d_out, int out_size, void* d_ws, size_t ws_size,
                              hipStream_t stream){
  const float* x    = (const float*)d_in[0];
  const float* h0   = (const float*)d_in[1];
  const float* wihf = (const float*)d_in[2];
  const float* whhf = (const float*)d_in[3];
  const float* bihf = (const float*)d_in[4];
  const float* bhhf = (const float*)d_in[5];
  const float* wihb = (const float*)d_in[6];
  const float* whhb = (const float*)d_in[7];
  const float* bihb = (const float*)d_in[8];
  const float* bhhb = (const float*)d_in[9];
  float* out = (float*)d_out;
  f16* wf16 = (f16*)d_ws;                            // 1 MB
  uint32_t* mail = (uint32_t*)d_ws + MAIL_OFF_U32;   // 256 KB

  hipMemsetAsync((void*)mail, 0, MAIL_BYTES, stream);  // kill stale tags across replays
  cvt_w_kernel<<<256, 256, 0, stream>>>(whhf, whhb, wf16);
  proj_kernel<<<dim3(128, 16), 256, 0, stream>>>(x, wihf, wihb, bihf, bhhf, bihb, bhhb, out);
  (void)hipFuncSetAttribute((const void*)rnn_kernel,
                            hipFuncAttributeMaxDynamicSharedMemorySize, LDS_TOTAL);
  rnn_kernel<<<256, 512, LDS_TOTAL, stream>>>(wf16, h0, out, mail);
}